// Round 1
// baseline (696.188 us; speedup 1.0000x reference)
//
#include <hip/hip_runtime.h>
#include <hip/hip_bf16.h>
#include <math.h>

// Problem constants (from reference): B=8, LQ=LKV=8192, H=8, E=64, K=64, MODES=64
#define B_   8
#define L_   8192
#define H_   8
#define E_   64
#define M_   64
#define K_   64
#define NC_  4            // t-chunks for DFT parallelism
#define TCH_ (L_/NC_)     // 2048

// Workspace layout (bytes):
//   P    : DFT partials [2][8][8][4][64m][2comp][64e] f32 = 16,777,216
//   X    : reduced DFT  [2][8][8][64m][64e] float2       =  4,194,304
//   XQK  : tanh scores  [8][8][64m][64l] float2          =  2,097,152
//   Y    : [8][8][64l][64e] float2                       =  2,097,152
//   V    : xqkvw [8][8][64l][64k] float2                 =  2,097,152
// total ≈ 27.3 MB
#define WS_P    0
#define WS_X    16777216
#define WS_XQK  20971520
#define WS_Y    23068672
#define WS_V    25165824

// ---------------- K1: partial DFT (the heavy kernel) ----------------
// X[tsr,b,h,m,e] = sum_t src[b,t,h,e] * exp(-2*pi*i * f_m * t / 8192),
// f_m = idx[m]. Each block: one (tsr,b,h) and one t-chunk of 2048; partial
// sums written to P. Thread layout: egrp=tid&7 (8 e's), mthr=tid>>3 (m, m+32).
__global__ __launch_bounds__(256) void k_dft(
    const float* __restrict__ q, const float* __restrict__ kk,
    const int* __restrict__ idxq, const int* __restrict__ idxkv,
    float* __restrict__ P) {
  __shared__ float2 cs[L_];   // 64 KB: (cos(2pi j/L), -sin(2pi j/L))
  const int tid = threadIdx.x;
  for (int j = tid; j < L_; j += 256) {
    float a = (float)j * (1.0f / 4096.0f);   // exact: j * 2^-12
    cs[j] = make_float2(cospif(a), -sinpif(a));
  }
  __syncthreads();

  const int bx  = blockIdx.x;
  const int c   = bx & 3;
  const int h   = (bx >> 2) & 7;
  const int b   = (bx >> 5) & 7;
  const int tsr = bx >> 8;            // 0=q, 1=k
  const float* src = tsr ? kk : q;
  const int*   idx = tsr ? idxkv : idxq;

  const int egrp = tid & 7, mthr = tid >> 3;
  const int e0 = egrp * 8;
  const int m1 = mthr, m2 = mthr + 32;
  const int f1 = idx[m1], f2 = idx[m2];
  const int t0 = c * TCH_;
  int j1 = (f1 * t0) & (L_ - 1);
  int j2 = (f2 * t0) & (L_ - 1);

  float ar1[8], ai1[8], ar2[8], ai2[8];
#pragma unroll
  for (int i = 0; i < 8; ++i) { ar1[i] = ai1[i] = ar2[i] = ai2[i] = 0.0f; }

  const float* p = src + ((size_t)b * L_ + t0) * (H_ * E_) + h * E_ + e0;
#pragma unroll 4
  for (int t = 0; t < TCH_; ++t) {
    const float4 v0 = *(const float4*)(p);
    const float4 v1 = *(const float4*)(p + 4);
    p += H_ * E_;
    const float2 w1 = cs[j1];
    const float2 w2 = cs[j2];
    j1 = (j1 + f1) & (L_ - 1);
    j2 = (j2 + f2) & (L_ - 1);
    const float v[8] = {v0.x, v0.y, v0.z, v0.w, v1.x, v1.y, v1.z, v1.w};
#pragma unroll
    for (int e = 0; e < 8; ++e) {
      ar1[e] = fmaf(v[e], w1.x, ar1[e]);
      ai1[e] = fmaf(v[e], w1.y, ai1[e]);
      ar2[e] = fmaf(v[e], w2.x, ar2[e]);
      ai2[e] = fmaf(v[e], w2.y, ai2[e]);
    }
  }

  // P[tsr][b][h][c][m][comp][e]
  float* pb = P + ((size_t)((tsr * 8 + b) * 8 + h) * NC_ + c) * (M_ * 2 * E_);
#define ST8(mm, comp, arr)                                                   \
  {                                                                          \
    float4* o = (float4*)(pb + ((mm) * 2 + (comp)) * E_ + e0);               \
    o[0] = make_float4(arr[0], arr[1], arr[2], arr[3]);                      \
    o[1] = make_float4(arr[4], arr[5], arr[6], arr[7]);                      \
  }
  ST8(m1, 0, ar1); ST8(m1, 1, ai1);
  ST8(m2, 0, ar2); ST8(m2, 1, ai2);
#undef ST8
}

// ---------------- K2: reduce t-chunk partials ----------------
__global__ __launch_bounds__(256) void k_reduce(const float* __restrict__ P,
                                                float2* __restrict__ X) {
  const int flat = blockIdx.x * 256 + threadIdx.x;  // 524288 total
  const int e = flat & 63;
  const int m = (flat >> 6) & 63;
  const int th = flat >> 12;                         // (tsr*8+b)*8+h
  const float* pb = P + (size_t)th * NC_ * (M_ * 2 * E_);
  float re = 0.0f, im = 0.0f;
#pragma unroll
  for (int c = 0; c < NC_; ++c) {
    re += pb[c * (M_ * 2 * E_) + (m * 2 + 0) * E_ + e];
    im += pb[c * (M_ * 2 * E_) + (m * 2 + 1) * E_ + e];
  }
  X[flat] = make_float2(re, im);
}

// ---------------- K3a: xqk[m][l] = tanh( sum_e Xq[l,e]*Xk[m,e] ) ----------------
__global__ __launch_bounds__(256) void k_xqk(const float2* __restrict__ X,
                                             float2* __restrict__ XQK) {
  __shared__ float2 sq[64 * 65];   // Xq[l][e], padded (lane index = l)
  __shared__ float2 sk[16 * 64];   // Xk rows for this m-group (broadcast reads)
  const int tid = threadIdx.x, bx = blockIdx.x;
  const int mg = bx & 3, h = (bx >> 2) & 7, b = bx >> 5;
  const float2* XQ = X + (size_t)(b * 8 + h) * 4096;
  const float2* XK = X + (size_t)(64 + b * 8 + h) * 4096;
  for (int i = tid; i < 4096; i += 256) sq[(i >> 6) * 65 + (i & 63)] = XQ[i];
  for (int i = tid; i < 1024; i += 256)
    sk[i] = XK[(mg * 16 + (i >> 6)) * 64 + (i & 63)];
  __syncthreads();

  const int l = tid & 63, mq = tid >> 6;
  float accr[4] = {0, 0, 0, 0}, acci[4] = {0, 0, 0, 0};
  for (int e = 0; e < 64; ++e) {
    const float2 aq = sq[l * 65 + e];
#pragma unroll
    for (int mi = 0; mi < 4; ++mi) {
      const float2 ak = sk[(mq * 4 + mi) * 64 + e];
      accr[mi] = fmaf(aq.x, ak.x, fmaf(-aq.y, ak.y, accr[mi]));
      acci[mi] = fmaf(aq.x, ak.y, fmaf(aq.y, ak.x, acci[mi]));
    }
  }
  float2* dst = XQK + (size_t)(b * 8 + h) * 4096;
#pragma unroll
  for (int mi = 0; mi < 4; ++mi) {
    const int m = mg * 16 + mq * 4 + mi;
    dst[m * 64 + l] = make_float2(tanhf(accr[mi]), tanhf(acci[mi]));
  }
}

// ---------------- K3b: Y[l][e] = sum_m xqk[m][l] * Xk[m][e] ----------------
__global__ __launch_bounds__(256) void k_y(const float2* __restrict__ X,
                                           const float2* __restrict__ XQK,
                                           float2* __restrict__ Y) {
  __shared__ float2 sp[64 * 64];   // xqk[m][l] (broadcast reads: l uniform/wave)
  __shared__ float2 sk[64 * 64];   // Xk[m][e]  (lane index = e)
  const int tid = threadIdx.x, bx = blockIdx.x;
  const int lg = bx & 3, h = (bx >> 2) & 7, b = bx >> 5;
  const float2* PP = XQK + (size_t)(b * 8 + h) * 4096;
  const float2* XK = X + (size_t)(64 + b * 8 + h) * 4096;
  for (int i = tid; i < 4096; i += 256) { sp[i] = PP[i]; sk[i] = XK[i]; }
  __syncthreads();

  const int e = tid & 63, lq = tid >> 6;
  float accr[4] = {0, 0, 0, 0}, acci[4] = {0, 0, 0, 0};
  for (int m = 0; m < 64; ++m) {
    const float2 kv = sk[m * 64 + e];
#pragma unroll
    for (int li = 0; li < 4; ++li) {
      const float2 pp = sp[m * 64 + lg * 16 + lq * 4 + li];
      accr[li] = fmaf(pp.x, kv.x, fmaf(-pp.y, kv.y, accr[li]));
      acci[li] = fmaf(pp.x, kv.y, fmaf(pp.y, kv.x, acci[li]));
    }
  }
  float2* dst = Y + (size_t)(b * 8 + h) * 4096;
#pragma unroll
  for (int li = 0; li < 4; ++li) {
    const int l = lg * 16 + lq * 4 + li;
    dst[l * 64 + e] = make_float2(accr[li], acci[li]);
  }
}

// ---------------- K3c: V[l][k] = sum_e Y[l][e] * (wr + i*wi)[l,h,e,k] ----------------
__global__ __launch_bounds__(256) void k_vw(const float2* __restrict__ Y,
                                            const float* __restrict__ WR,
                                            const float* __restrict__ WI,
                                            float2* __restrict__ V) {
  __shared__ float2 sy[16 * 64];
  const int tid = threadIdx.x, bx = blockIdx.x;
  const int lg = bx & 3, h = (bx >> 2) & 7, b = bx >> 5;
  const float2* YY = Y + (size_t)(b * 8 + h) * 4096;
  for (int i = tid; i < 1024; i += 256)
    sy[i] = YY[(lg * 16 + (i >> 6)) * 64 + (i & 63)];
  __syncthreads();

  const int k = tid & 63, lq = tid >> 6;
  float accr[4] = {0, 0, 0, 0}, acci[4] = {0, 0, 0, 0};
  for (int e = 0; e < 64; ++e) {
#pragma unroll
    for (int li = 0; li < 4; ++li) {
      const int lloc = lq * 4 + li;
      const int l = lg * 16 + lloc;
      const float2 y = sy[lloc * 64 + e];
      const size_t wb = ((size_t)(l * 8 + h) * 64 + e) * 64 + k;
      const float wr = WR[wb], wi = WI[wb];
      accr[li] = fmaf(y.x, wr, fmaf(-y.y, wi, accr[li]));
      acci[li] = fmaf(y.x, wi, fmaf(y.y, wr, acci[li]));
    }
  }
  float2* dst = V + (size_t)(b * 8 + h) * 4096;
#pragma unroll
  for (int li = 0; li < 4; ++li)
    dst[(lg * 16 + lq * 4 + li) * 64 + k] = make_float2(accr[li], acci[li]);
}

// ---------------- K4: scatter + irfft(n=64) + scale ----------------
// out[b,t,h,k] = 2^-24 * [ S0.re + 2*sum_{f=1..31}(Sf.re*cos - Sf.im*sin) + S32.re*(-1)^t ]
// where S[f] = V[b,h,l,k] with idx_q[l]==f (later l wins, matching .at[].set).
__global__ __launch_bounds__(256) void k_irfft(const float2* __restrict__ V,
                                               const int* __restrict__ idxq,
                                               float* __restrict__ out) {
  __shared__ float2 S[33 * 64];
  __shared__ float2 tt[64];
  __shared__ int inv[33];
  const int tid = threadIdx.x, bx = blockIdx.x;
  const int h = bx & 7, b = bx >> 3;
  if (tid < 64) {
    const float a = (float)tid * (1.0f / 32.0f);   // 2*pi*j/64 = pi*j/32
    tt[tid] = make_float2(cospif(a), sinpif(a));
  }
  if (tid < 33) inv[tid] = -1;
  __syncthreads();
  if (tid == 0) {
    for (int l = 0; l < 64; ++l) {
      const int v = idxq[l];
      if (v >= 0 && v < 33) inv[v] = l;   // later index overwrites (set semantics)
    }
  }
  __syncthreads();
  const float2* VV = V + (size_t)(b * 8 + h) * 4096;
  for (int i = tid; i < 33 * 64; i += 256) {
    const int f = i >> 6, k = i & 63;
    const int l = inv[f];
    S[i] = (l >= 0) ? VV[l * 64 + k] : make_float2(0.0f, 0.0f);
  }
  __syncthreads();

  const int k = tid & 63, tg = tid >> 6;
  for (int ti = 0; ti < 16; ++ti) {
    const int t = tg * 16 + ti;
    float acc = 0.0f;
#pragma unroll
    for (int f = 0; f <= 32; ++f) {
      const float2 s = S[f * 64 + k];
      const float2 w = tt[(f * t) & 63];
      const float wf = (f == 0 || f == 32) ? 1.0f : 2.0f;
      acc += wf * (s.x * w.x - s.y * w.y);
    }
    out[(((size_t)b * 64 + t) * 8 + h) * 64 + k] = acc * (1.0f / 16777216.0f);
  }
}

extern "C" void kernel_launch(void* const* d_in, const int* in_sizes, int n_in,
                              void* d_out, int out_size, void* d_ws, size_t ws_size,
                              hipStream_t stream) {
  const float* q  = (const float*)d_in[0];
  const float* k  = (const float*)d_in[1];
  // d_in[2] = v (unused by reference), d_in[3] = mask (unused)
  const float* wr = (const float*)d_in[4];
  const float* wi = (const float*)d_in[5];
  const int* iq   = (const int*)d_in[6];
  const int* ikv  = (const int*)d_in[7];
  float* out = (float*)d_out;

  char* ws = (char*)d_ws;
  float*  P   = (float*)(ws + WS_P);
  float2* X   = (float2*)(ws + WS_X);
  float2* XQK = (float2*)(ws + WS_XQK);
  float2* Y   = (float2*)(ws + WS_Y);
  float2* V   = (float2*)(ws + WS_V);

  k_dft  <<<2 * B_ * H_ * NC_, 256, 0, stream>>>(q, k, iq, ikv, P);
  k_reduce<<<2048, 256, 0, stream>>>(P, X);
  k_xqk  <<<B_ * H_ * 4, 256, 0, stream>>>(X, XQK);
  k_y    <<<B_ * H_ * 4, 256, 0, stream>>>(X, XQK, Y);
  k_vw   <<<B_ * H_ * 4, 256, 0, stream>>>(Y, wr, wi, V);
  k_irfft<<<B_ * H_, 256, 0, stream>>>(V, iq, out);
}

// Round 4
// 517.506 us; speedup vs baseline: 1.3453x; 1.3453x over previous
//
#include <hip/hip_runtime.h>
#include <hip/hip_bf16.h>
#include <math.h>

// Problem constants: B=8, LQ=LKV=8192, H=8, E=64, K=64, MODES=64
#define B_   8
#define L_   8192
#define H_   8
#define E_   64
#define M_   64
#define K_   64

// ---------------- async global->LDS helper (16B per lane) ----------------
__device__ __forceinline__ void async_copy16(void* lds, const void* g) {
  __builtin_amdgcn_global_load_lds(
      (const __attribute__((address_space(1))) unsigned int*)g,
      (__attribute__((address_space(3))) unsigned int*)lds,
      16, 0, 0);
}

// ---------------- K1: partial DFT ----------------
// X[tsr,b,h,m,e] = sum_t src[b,t,h,e] * exp(-2*pi*i * f_m * t / 8192).
// Block = (tsr,b,h,c): one t-chunk of L/NC rows. 512 threads:
//   sub = tid>>8 (t parity), m = (tid>>2)&63, e-slice = (tid&3)*16.
// Data staged 32 rows (8 KB) at a time into LDS via global_load_lds (dbuf).
// Twiddle table: 4096 float2 (32 KB) half-period + sign trick; incremental
// byte-offset indexing j8 += 16*f (mod 64K).
template <int NC>
__global__ __launch_bounds__(512, 4) void k_dft(
    const float* __restrict__ q, const float* __restrict__ kk,
    const int* __restrict__ idxq, const int* __restrict__ idxkv,
    float* __restrict__ P) {
  constexpr int CHUNK = L_ / NC;
  constexpr int NSTAGE = CHUNK / 32;
  __shared__ float2 cs[4096];        // 32 KB: (cos, -sin)(2*pi*j/8192), j<4096
  __shared__ float  sx[2][32 * 64];  // 2 x 8 KB row staging
  const int tid = threadIdx.x;
  for (int j = tid; j < 4096; j += 512) {
    // entry j holds angle 2*pi*j/8192 = pi * (j/4096)
    float a = (float)j * (1.0f / 4096.0f);
    cs[j] = make_float2(cospif(a), -sinpif(a));
  }

  const int bx  = blockIdx.x;
  const int c   = bx % NC;
  const int h   = (bx / NC) & 7;
  const int b   = (bx / (NC * 8)) & 7;
  const int tsr = bx / (NC * 64);
  const float* src = tsr ? kk : q;
  const int*   idx = tsr ? idxkv : idxq;

  const int sub = tid >> 8;          // 0/1: even/odd t
  const int r   = tid & 255;
  const int m   = r >> 2;
  const int e0  = (r & 3) * 16;
  const int f   = idx[m];
  const int t0  = c * CHUNK;

  unsigned j8 = (unsigned)(((long long)f * (t0 + sub)) & 8191) * 8u;
  const unsigned fstep = ((unsigned)f * 16u) & 0xFFFFu;

  float ar[16], ai[16];
#pragma unroll
  for (int i = 0; i < 16; ++i) { ar[i] = 0.f; ai[i] = 0.f; }

  const int srow = tid >> 4;   // staging row 0..31
  const float* gbase = src + ((size_t)b * L_ + t0) * (H_ * E_) + h * E_ + (tid & 15) * 4;

  // prologue: stage 0 (table fill synced by the same barrier)
  async_copy16(&sx[0][0] + (size_t)tid * 4, gbase + (size_t)srow * (H_ * E_));
  asm volatile("s_waitcnt vmcnt(0)" ::: "memory");
  __syncthreads();

  for (int s = 0; s < NSTAGE; ++s) {
    const int cur = s & 1;
    if (s + 1 < NSTAGE) {
      async_copy16(&sx[cur ^ 1][0] + (size_t)tid * 4,
                   gbase + (size_t)((s + 1) * 32 + srow) * (H_ * E_));
    }
    const float* row = &sx[cur][0];
#pragma unroll
    for (int i = 0; i < 16; ++i) {
      const int rr = 2 * i + sub;
      const float4 d0 = *(const float4*)(row + rr * 64 + e0);
      const float4 d1 = *(const float4*)(row + rr * 64 + e0 + 4);
      const float4 d2 = *(const float4*)(row + rr * 64 + e0 + 8);
      const float4 d3 = *(const float4*)(row + rr * 64 + e0 + 12);
      const unsigned jb = j8 & 0x7FFFu;
      const unsigned sg = (j8 & 0x8000u) << 16;
      float2 w = *(const float2*)((const char*)cs + jb);
      w.x = __uint_as_float(__float_as_uint(w.x) ^ sg);
      w.y = __uint_as_float(__float_as_uint(w.y) ^ sg);
      j8 = (j8 + fstep) & 0xFFFFu;
#define CFMA(IDX, VAL)                          \
      ar[IDX] = fmaf((VAL), w.x, ar[IDX]);      \
      ai[IDX] = fmaf((VAL), w.y, ai[IDX]);
      CFMA(0, d0.x)  CFMA(1, d0.y)  CFMA(2, d0.z)  CFMA(3, d0.w)
      CFMA(4, d1.x)  CFMA(5, d1.y)  CFMA(6, d1.z)  CFMA(7, d1.w)
      CFMA(8, d2.x)  CFMA(9, d2.y)  CFMA(10, d2.z) CFMA(11, d2.w)
      CFMA(12, d3.x) CFMA(13, d3.y) CFMA(14, d3.z) CFMA(15, d3.w)
#undef CFMA
    }
    asm volatile("s_waitcnt vmcnt(0)" ::: "memory");
    __syncthreads();
  }

  // cross-sub reduction via LDS (reuse sx: 4096 floats)
  float* red = &sx[0][0];
  if (sub == 1) {
#pragma unroll
    for (int i = 0; i < 16; ++i) red[r * 16 + i] = ar[i];
  }
  __syncthreads();
  if (sub == 0) {
#pragma unroll
    for (int i = 0; i < 16; ++i) ar[i] += red[r * 16 + i];
  }
  __syncthreads();
  if (sub == 1) {
#pragma unroll
    for (int i = 0; i < 16; ++i) red[r * 16 + i] = ai[i];
  }
  __syncthreads();
  if (sub == 0) {
#pragma unroll
    for (int i = 0; i < 16; ++i) ai[i] += red[r * 16 + i];
    // P[tsr][b][h][c][m][comp][e]
    float* pb = P + ((size_t)((tsr * 8 + b) * 8 + h) * NC + c) * (M_ * 2 * E_) + m * 128;
    float4* o0 = (float4*)(pb + e0);
    o0[0] = make_float4(ar[0], ar[1], ar[2], ar[3]);
    o0[1] = make_float4(ar[4], ar[5], ar[6], ar[7]);
    o0[2] = make_float4(ar[8], ar[9], ar[10], ar[11]);
    o0[3] = make_float4(ar[12], ar[13], ar[14], ar[15]);
    float4* o1 = (float4*)(pb + 64 + e0);
    o1[0] = make_float4(ai[0], ai[1], ai[2], ai[3]);
    o1[1] = make_float4(ai[4], ai[5], ai[6], ai[7]);
    o1[2] = make_float4(ai[8], ai[9], ai[10], ai[11]);
    o1[3] = make_float4(ai[12], ai[13], ai[14], ai[15]);
  }
}

// ---------------- K2: reduce t-chunk partials ----------------
__global__ __launch_bounds__(256) void k_reduce(const float* __restrict__ P,
                                                float2* __restrict__ X, int nc) {
  const int flat = blockIdx.x * 256 + threadIdx.x;  // 524288 total
  const int e = flat & 63;
  const int m = (flat >> 6) & 63;
  const int th = flat >> 12;
  const float* pb = P + (size_t)th * nc * (M_ * 2 * E_);
  float re = 0.0f, im = 0.0f;
  for (int c = 0; c < nc; ++c) {
    re += pb[c * (M_ * 2 * E_) + (m * 2 + 0) * E_ + e];
    im += pb[c * (M_ * 2 * E_) + (m * 2 + 1) * E_ + e];
  }
  X[flat] = make_float2(re, im);
}

// ---------------- K3a: xqk[m][l] = tanh( sum_e Xq[l,e]*Xk[m,e] ) ----------------
__global__ __launch_bounds__(256) void k_xqk(const float2* __restrict__ X,
                                             float2* __restrict__ XQK) {
  __shared__ float2 sq[64 * 65];
  __shared__ float2 sk[16 * 64];
  const int tid = threadIdx.x, bx = blockIdx.x;
  const int mg = bx & 3, h = (bx >> 2) & 7, b = bx >> 5;
  const float2* XQ = X + (size_t)(b * 8 + h) * 4096;
  const float2* XK = X + (size_t)(64 + b * 8 + h) * 4096;
  for (int i = tid; i < 4096; i += 256) sq[(i >> 6) * 65 + (i & 63)] = XQ[i];
  for (int i = tid; i < 1024; i += 256)
    sk[i] = XK[(mg * 16 + (i >> 6)) * 64 + (i & 63)];
  __syncthreads();

  const int l = tid & 63, mq = tid >> 6;
  float accr[4] = {0, 0, 0, 0}, acci[4] = {0, 0, 0, 0};
  for (int e = 0; e < 64; ++e) {
    const float2 aq = sq[l * 65 + e];
#pragma unroll
    for (int mi = 0; mi < 4; ++mi) {
      const float2 ak = sk[(mq * 4 + mi) * 64 + e];
      accr[mi] = fmaf(aq.x, ak.x, fmaf(-aq.y, ak.y, accr[mi]));
      acci[mi] = fmaf(aq.x, ak.y, fmaf(aq.y, ak.x, acci[mi]));
    }
  }
  float2* dst = XQK + (size_t)(b * 8 + h) * 4096;
#pragma unroll
  for (int mi = 0; mi < 4; ++mi) {
    const int m = mg * 16 + mq * 4 + mi;
    dst[m * 64 + l] = make_float2(tanhf(accr[mi]), tanhf(acci[mi]));
  }
}

// ---------------- K3b: Y[l][e] = sum_m xqk[m][l] * Xk[m][e] ----------------
__global__ __launch_bounds__(256) void k_y(const float2* __restrict__ X,
                                           const float2* __restrict__ XQK,
                                           float2* __restrict__ Y) {
  __shared__ float2 sp[64 * 64];
  __shared__ float2 sk[64 * 64];
  const int tid = threadIdx.x, bx = blockIdx.x;
  const int lg = bx & 3, h = (bx >> 2) & 7, b = bx >> 5;
  const float2* PP = XQK + (size_t)(b * 8 + h) * 4096;
  const float2* XK = X + (size_t)(64 + b * 8 + h) * 4096;
  for (int i = tid; i < 4096; i += 256) { sp[i] = PP[i]; sk[i] = XK[i]; }
  __syncthreads();

  const int e = tid & 63, lq = tid >> 6;
  float accr[4] = {0, 0, 0, 0}, acci[4] = {0, 0, 0, 0};
  for (int m = 0; m < 64; ++m) {
    const float2 kv = sk[m * 64 + e];
#pragma unroll
    for (int li = 0; li < 4; ++li) {
      const float2 pp = sp[m * 64 + lg * 16 + lq * 4 + li];
      accr[li] = fmaf(pp.x, kv.x, fmaf(-pp.y, kv.y, accr[li]));
      acci[li] = fmaf(pp.x, kv.y, fmaf(pp.y, kv.x, acci[li]));
    }
  }
  float2* dst = Y + (size_t)(b * 8 + h) * 4096;
#pragma unroll
  for (int li = 0; li < 4; ++li) {
    const int l = lg * 16 + lq * 4 + li;
    dst[l * 64 + e] = make_float2(accr[li], acci[li]);
  }
}

// ---------------- K3c: V[b,l,h,k] = sum_e Y[b,l,h,e] * W[l,h,e,k] ----------------
// Grid over (l,h): weights read exactly once (16.8 MB), batch inside.
__global__ __launch_bounds__(256) void k_vw(const float2* __restrict__ Y,
                                            const float* __restrict__ WR,
                                            const float* __restrict__ WI,
                                            float2* __restrict__ V) {
  __shared__ float2 sy[8][64];   // Y[b][e] for this (l,h)
  const int tid = threadIdx.x, bx = blockIdx.x;
  const int h = bx & 7, l = bx >> 3;
  for (int i = tid; i < 512; i += 256) {
    const int b = i >> 6, e = i & 63;
    sy[b][e] = Y[(size_t)(b * 8 + h) * 4096 + l * 64 + e];
  }
  __syncthreads();
  const int k = tid & 63, bq = tid >> 6;   // bq in [0,4): handles b=bq, bq+4
  float ar0 = 0, ai0 = 0, ar1 = 0, ai1 = 0;
  const float* wr = WR + ((size_t)(l * 8 + h) * 64) * 64 + k;
  const float* wi = WI + ((size_t)(l * 8 + h) * 64) * 64 + k;
#pragma unroll 8
  for (int e = 0; e < 64; ++e) {
    const float rw = wr[e * 64], iw = wi[e * 64];
    const float2 y0 = sy[bq][e], y1 = sy[bq + 4][e];
    ar0 = fmaf(y0.x, rw, fmaf(-y0.y, iw, ar0));
    ai0 = fmaf(y0.x, iw, fmaf(y0.y, rw, ai0));
    ar1 = fmaf(y1.x, rw, fmaf(-y1.y, iw, ar1));
    ai1 = fmaf(y1.x, iw, fmaf(y1.y, rw, ai1));
  }
  V[(size_t)(bq * 8 + h) * 4096 + l * 64 + k] = make_float2(ar0, ai0);
  V[(size_t)((bq + 4) * 8 + h) * 4096 + l * 64 + k] = make_float2(ar1, ai1);
}

// ---------------- K4: scatter + irfft(n=64) + scale ----------------
__global__ __launch_bounds__(256) void k_irfft(const float2* __restrict__ V,
                                               const int* __restrict__ idxq,
                                               float* __restrict__ out) {
  __shared__ float2 S[33 * 64];
  __shared__ float2 tt[64];
  __shared__ int inv[33];
  const int tid = threadIdx.x, bx = blockIdx.x;
  const int tq = bx & 3, h = (bx >> 2) & 7, b = bx >> 5;
  if (tid < 64) {
    const float a = (float)tid * (1.0f / 32.0f);
    tt[tid] = make_float2(cospif(a), sinpif(a));
  }
  if (tid < 33) inv[tid] = -1;
  __syncthreads();
  if (tid == 0) {
    for (int l = 0; l < 64; ++l) {
      const int v = idxq[l];
      if (v >= 0 && v < 33) inv[v] = l;   // later index wins (set semantics)
    }
  }
  __syncthreads();
  const float2* VV = V + (size_t)(b * 8 + h) * 4096;
  for (int i = tid; i < 33 * 64; i += 256) {
    const int f = i >> 6, k = i & 63;
    const int l = inv[f];
    S[i] = (l >= 0) ? VV[l * 64 + k] : make_float2(0.0f, 0.0f);
  }
  __syncthreads();

  const int k = tid & 63, tl = tid >> 6;
  for (int ti = 0; ti < 4; ++ti) {
    const int t = tq * 16 + tl * 4 + ti;
    float acc = 0.0f;
#pragma unroll
    for (int f = 0; f <= 32; ++f) {
      const float2 s = S[f * 64 + k];
      const float2 w = tt[(f * t) & 63];
      const float wf = (f == 0 || f == 32) ? 1.0f : 2.0f;
      acc += wf * (s.x * w.x - s.y * w.y);
    }
    out[(((size_t)b * 64 + t) * 8 + h) * 64 + k] = acc * (1.0f / 16777216.0f);
  }
}

extern "C" void kernel_launch(void* const* d_in, const int* in_sizes, int n_in,
                              void* d_out, int out_size, void* d_ws, size_t ws_size,
                              hipStream_t stream) {
  const float* q  = (const float*)d_in[0];
  const float* k  = (const float*)d_in[1];
  // d_in[2] = v (unused), d_in[3] = mask (unused)
  const float* wr = (const float*)d_in[4];
  const float* wi = (const float*)d_in[5];
  const int* iq   = (const int*)d_in[6];
  const int* ikv  = (const int*)d_in[7];
  float* out = (float*)d_out;

  // choose NC by available workspace: NC=8 needs ~44 MB total
  const int nc = (ws_size >= (size_t)46 * 1024 * 1024) ? 8 : 4;
  char* ws = (char*)d_ws;
  const size_t pbytes = (size_t)(2 * 8 * 8) * nc * (M_ * 2 * E_) * 4;
  float*  P   = (float*)ws;
  float2* X   = (float2*)(ws + pbytes);
  float2* XQK = (float2*)(ws + pbytes + 4194304);
  float2* Y   = (float2*)(ws + pbytes + 4194304 + 2097152);
  float2* V   = (float2*)(ws + pbytes + 4194304 + 2 * 2097152);

  if (nc == 8) k_dft<8><<<128 * 8, 512, 0, stream>>>(q, k, iq, ikv, P);
  else         k_dft<4><<<128 * 4, 512, 0, stream>>>(q, k, iq, ikv, P);
  k_reduce<<<2048, 256, 0, stream>>>(P, X, nc);
  k_xqk  <<<B_ * H_ * 4, 256, 0, stream>>>(X, XQK);
  k_y    <<<B_ * H_ * 4, 256, 0, stream>>>(X, XQK, Y);
  k_vw   <<<M_ * H_, 256, 0, stream>>>(Y, wr, wi, V);
  k_irfft<<<B_ * H_ * 4, 256, 0, stream>>>(V, iq, out);
}